// Round 1
// baseline (9935.204 us; speedup 1.0000x reference)
//
#include <hip/hip_runtime.h>
#include <math.h>

typedef unsigned long long ull;

#define MEMD 100
#define RAWD 172
#define TDD  100
#define AGG  472   // 2*MEM + RAW + TD
#define KTOT 572   // AGG + MEM (h appended for the hh-gates)
#define TB   32    // nodes per block
#define NTH  320   // 32 node-lanes x 10 out-lanes
#define QPT  10    // output channels per thread per gate

// ---------------- Phase B: per-node lexicographic argmax over (t, event idx) ----
__global__ void ev_scatter(const int* __restrict__ loc_s, const int* __restrict__ t_s,
                           const int* __restrict__ loc_d, const int* __restrict__ t_d,
                           ull* __restrict__ keys, int E)
{
    int e = blockIdx.x * blockDim.x + threadIdx.x;
    if (e >= 2 * E) return;
    int loc, t;
    if (e < E) { loc = loc_s[e];     t = t_s[e]; }
    else       { loc = loc_d[e - E]; t = t_d[e - E]; }
    // key = (t+1) << 20 | e  -> max over events == lexicographic (t, e) max.
    // t < 2^19, e < 2^20 here; key==0 is the "no event" sentinel.
    ull key = (((ull)(unsigned)(t + 1)) << 20) | (ull)(unsigned)e;
    atomicMax(&keys[loc], key);
}

// ---------------- Phase C: build msg tile + fused GRU -------------------------
__global__ __launch_bounds__(NTH)
void tgn_update(const float* __restrict__ memory, const int* __restrict__ last_update,
                const int* __restrict__ n_id,
                const int* __restrict__ dst_s, const float* __restrict__ raw_s,
                const int* __restrict__ dst_d, const float* __restrict__ raw_d,
                const float* __restrict__ time_w, const float* __restrict__ time_b,
                const float* __restrict__ W_ih, const float* __restrict__ W_hh,
                const float* __restrict__ b_ih, const float* __restrict__ b_hh,
                const ull* __restrict__ keys,
                float* __restrict__ out_mem, float* __restrict__ out_lu,
                int N, int E)
{
    // [k][i] layout, +1 pad => stride 33 floats: conflict-free across node lanes
    __shared__ float msg[KTOT][TB + 1];
    __shared__ int   sh_e[TB];
    __shared__ int   sh_dst[TB];
    __shared__ int   sh_src[TB];
    __shared__ float sh_trel[TB];

    const int tid  = threadIdx.x;
    const int base = blockIdx.x * TB;

    if (tid < TB) {
        const int i = tid;
        const int j = base + i;
        int e = -1, dst = 0, src = 0;
        float trel = 0.f;
        if (j < N) {
            src = n_id[j];
            int lu = last_update[src];
            ull key = keys[j];
            if (key != 0ull) {
                e = (int)(key & 0xFFFFFull);
                int te = (int)(key >> 20) - 1;
                trel = (float)(te - lu);
                dst = (e < E) ? dst_s[e] : dst_d[e - E];
                if (te > lu) lu = te;
            }
            out_lu[j] = (float)lu;   // ints < 2^24: exact in f32
        }
        sh_e[i] = e; sh_dst[i] = dst; sh_src[i] = src; sh_trel[i] = trel;
    }
    __syncthreads();

    // --- fill msg tile ---
    // h -> rows [AGG, AGG+100) always; rows [0,100) if node has an event
    for (int idx = tid; idx < TB * MEMD; idx += NTH) {
        int i = idx / MEMD, c = idx % MEMD;
        int j = base + i;
        float v = 0.f;
        if (j < N) v = memory[(size_t)sh_src[i] * MEMD + c];
        msg[AGG + c][i] = v;
        msg[c][i] = (sh_e[i] >= 0) ? v : 0.f;
    }
    // memory[dst] -> rows [100,200)
    for (int idx = tid; idx < TB * MEMD; idx += NTH) {
        int i = idx / MEMD, c = idx % MEMD;
        float v = 0.f;
        if (sh_e[i] >= 0) v = memory[(size_t)sh_dst[i] * MEMD + c];
        msg[MEMD + c][i] = v;
    }
    // raw msg -> rows [200,372)
    for (int idx = tid; idx < TB * RAWD; idx += NTH) {
        int i = idx / RAWD, c = idx % RAWD;
        int e = sh_e[i];
        float v = 0.f;
        if (e >= 0) {
            const float* rp = (e < E) ? (raw_s + (size_t)e * RAWD)
                                      : (raw_d + (size_t)(e - E) * RAWD);
            v = rp[c];
        }
        msg[2 * MEMD + c][i] = v;
    }
    // time encoding -> rows [372,472)
    for (int idx = tid; idx < TB * TDD; idx += NTH) {
        int i = idx / TDD, c = idx % TDD;
        float v = 0.f;
        if (sh_e[i] >= 0) v = cosf(sh_trel[i] * time_w[c] + time_b[c]);
        msg[2 * MEMD + RAWD + c][i] = v;
    }
    __syncthreads();

    // --- register-tiled fp32 GEMM: 4 accumulator sets (r, z, i_n, h_n) ---
    const int i  = tid & (TB - 1);   // node lane
    const int g  = tid / TB;         // out-lane 0..9
    const int c0 = g * QPT;

    float aR[QPT], aZ[QPT], aN[QPT], aH[QPT];
    #pragma unroll
    for (int q = 0; q < QPT; q++) { aR[q] = 0.f; aZ[q] = 0.f; aN[q] = 0.f; aH[q] = 0.f; }

    const float* Wr = W_ih + (size_t)c0 * AGG;
    const float* Wz = W_ih + (size_t)(MEMD + c0) * AGG;
    const float* Wn = W_ih + (size_t)(2 * MEMD + c0) * AGG;

    for (int k = 0; k < AGG; k += 4) {
        float m0 = msg[k + 0][i], m1 = msg[k + 1][i], m2 = msg[k + 2][i], m3 = msg[k + 3][i];
        #pragma unroll
        for (int q = 0; q < QPT; q++) {
            float4 wr = *(const float4*)(Wr + (size_t)q * AGG + k);
            float4 wz = *(const float4*)(Wz + (size_t)q * AGG + k);
            float4 wn = *(const float4*)(Wn + (size_t)q * AGG + k);
            aR[q] += m0 * wr.x + m1 * wr.y + m2 * wr.z + m3 * wr.w;
            aZ[q] += m0 * wz.x + m1 * wz.y + m2 * wz.z + m3 * wz.w;
            aN[q] += m0 * wn.x + m1 * wn.y + m2 * wn.z + m3 * wn.w;
        }
    }

    const float* Hr = W_hh + (size_t)c0 * MEMD;
    const float* Hz = W_hh + (size_t)(MEMD + c0) * MEMD;
    const float* Hn = W_hh + (size_t)(2 * MEMD + c0) * MEMD;

    for (int k = 0; k < MEMD; k += 4) {
        float m0 = msg[AGG + k + 0][i], m1 = msg[AGG + k + 1][i];
        float m2 = msg[AGG + k + 2][i], m3 = msg[AGG + k + 3][i];
        #pragma unroll
        for (int q = 0; q < QPT; q++) {
            float4 wr = *(const float4*)(Hr + (size_t)q * MEMD + k);
            float4 wz = *(const float4*)(Hz + (size_t)q * MEMD + k);
            float4 wn = *(const float4*)(Hn + (size_t)q * MEMD + k);
            aR[q] += m0 * wr.x + m1 * wr.y + m2 * wr.z + m3 * wr.w;
            aZ[q] += m0 * wz.x + m1 * wz.y + m2 * wz.z + m3 * wz.w;
            aH[q] += m0 * wn.x + m1 * wn.y + m2 * wn.z + m3 * wn.w;
        }
    }

    __syncthreads();   // everyone done reading msg before we overwrite rows [0,100)

    // --- gate epilogue (fully thread-local) ---
    #pragma unroll
    for (int q = 0; q < QPT; q++) {
        int c = c0 + q;
        float r  = 1.f / (1.f + __expf(-(aR[q] + b_ih[c] + b_hh[c])));
        float z  = 1.f / (1.f + __expf(-(aZ[q] + b_ih[MEMD + c] + b_hh[MEMD + c])));
        float pre = aN[q] + b_ih[2 * MEMD + c] + r * (aH[q] + b_hh[2 * MEMD + c]);
        float ex = __expf(2.f * pre);
        float th = 1.f - 2.f / (ex + 1.f);    // tanh, inf-safe
        float h  = msg[AGG + c][i];
        msg[c][i] = (1.f - z) * th + z * h;
    }
    __syncthreads();

    // coalesced store of new_memory
    for (int idx = tid; idx < TB * MEMD; idx += NTH) {
        int i2 = idx / MEMD, c = idx % MEMD;
        int j = base + i2;
        if (j < N) out_mem[(size_t)j * MEMD + c] = msg[c][i2];
    }
}

extern "C" void kernel_launch(void* const* d_in, const int* in_sizes, int n_in,
                              void* d_out, int out_size, void* d_ws, size_t ws_size,
                              hipStream_t stream)
{
    const float* memory      = (const float*)d_in[0];
    const int*   last_update = (const int*)  d_in[1];
    const int*   n_id        = (const int*)  d_in[2];
    const int*   loc_s       = (const int*)  d_in[3];
    const int*   dst_s       = (const int*)  d_in[4];
    const int*   t_s         = (const int*)  d_in[5];
    const float* raw_s       = (const float*)d_in[6];
    const int*   loc_d       = (const int*)  d_in[7];
    const int*   dst_d       = (const int*)  d_in[8];
    const int*   t_d         = (const int*)  d_in[9];
    const float* raw_d       = (const float*)d_in[10];
    const float* time_w      = (const float*)d_in[11];
    const float* time_b      = (const float*)d_in[12];
    const float* W_ih        = (const float*)d_in[13];
    const float* W_hh        = (const float*)d_in[14];
    const float* b_ih        = (const float*)d_in[15];
    const float* b_hh        = (const float*)d_in[16];

    const int N = in_sizes[2];   // 200000
    const int E = in_sizes[3];   // 100000

    ull*   keys    = (ull*)d_ws;                    // N * 8 bytes
    float* out_mem = (float*)d_out;                 // [N,100]
    float* out_lu  = out_mem + (size_t)N * MEMD;    // [N] (as float)

    hipMemsetAsync(keys, 0, (size_t)N * sizeof(ull), stream);

    ev_scatter<<<(2 * E + 255) / 256, 256, 0, stream>>>(loc_s, t_s, loc_d, t_d, keys, E);

    tgn_update<<<(N + TB - 1) / TB, NTH, 0, stream>>>(
        memory, last_update, n_id,
        dst_s, raw_s, dst_d, raw_d,
        time_w, time_b, W_ih, W_hh, b_ih, b_hh,
        keys, out_mem, out_lu, N, E);
}